// Round 2
// baseline (320.412 us; speedup 1.0000x reference)
//
#include <hip/hip_runtime.h>

// NeRF volume render: B rays x S=64 samples.
// 4 threads per ray, 16 samples per thread (sequential cumprod in registers),
// 3-shuffle 4-lane scan to stitch quarter transmittances, 8-shuffle reduce.
//
// alpha_i = 1 - exp(-sigma_i); v_i = exp(-sigma_i) + 1e-10
// T_i = prod_{j<i} v_j ; w_i = alpha_i * T_i
// rgb_map = sum w_i * rgb_i ; depth = sum w_i * t_i, t = linspace(2,6,64)

#define NSAMP 64
#define QS 16           // samples per thread
#define TPR 4           // threads per ray

__global__ __launch_bounds__(256, 4) void nerf_render_kernel(
    const float* __restrict__ rgb,     // [B, 64, 3]
    const float* __restrict__ sigma,   // [B, 64]
    float* __restrict__ rgb_map,       // [B, 3]
    float* __restrict__ depth_map,     // [B]
    int n_rays)
{
    const int tid = blockIdx.x * blockDim.x + threadIdx.x;
    const int ray = tid >> 2;          // 4 threads per ray
    const int q   = tid & 3;           // quarter index
    if (ray >= n_rays) return;

    // sigma chunk: floats [16*tid, 16*tid+16) -> byte offset 64*tid (16B aligned)
    const float4* sg4 = (const float4*)(sigma + (size_t)tid * QS);
    // rgb chunk: floats [48*tid, 48*tid+48) -> byte offset 192*tid (16B aligned)
    const float4* rg4 = (const float4*)(rgb + (size_t)tid * (QS * 3));

    // Issue sigma loads first (compute depends on them), then rgb.
    float sg[QS];
    #pragma unroll
    for (int k = 0; k < QS / 4; ++k) {
        float4 v = sg4[k];
        sg[4*k+0] = v.x; sg[4*k+1] = v.y; sg[4*k+2] = v.z; sg[4*k+3] = v.w;
    }
    float rg[QS * 3];
    #pragma unroll
    for (int k = 0; k < (QS * 3) / 4; ++k) {
        float4 v = rg4[k];
        rg[4*k+0] = v.x; rg[4*k+1] = v.y; rg[4*k+2] = v.z; rg[4*k+3] = v.w;
    }

    // Sequential 16-sample pass with quarter-local transmittance.
    const float tstep = 4.0f / 63.0f;
    const float tbase = 2.0f + (float)(q * QS) * tstep;
    float T = 1.0f;
    float cr = 0.0f, cg = 0.0f, cb = 0.0f, cd = 0.0f;
    #pragma unroll
    for (int j = 0; j < QS; ++j) {
        float e = __expf(-sg[j]);
        float a = 1.0f - e;          // alpha
        float v = e + 1e-10f;        // 1 - alpha + eps
        float w = a * T;
        T *= v;
        cr = fmaf(w, rg[3*j+0], cr);
        cg = fmaf(w, rg[3*j+1], cg);
        cb = fmaf(w, rg[3*j+2], cb);
        cd = fmaf(w, tbase + (float)j * tstep, cd);
    }

    // T now = product of v over this quarter. Exclusive prefix across the
    // 4 lanes of this ray (Hillis-Steele within width-4 groups): 3 shuffles.
    float P = T;
    float o1 = __shfl_up(P, 1, TPR); if (q >= 1) P *= o1;
    float o2 = __shfl_up(P, 2, TPR); if (q >= 2) P *= o2;
    float pref = __shfl_up(P, 1, TPR); if (q == 0) pref = 1.0f;

    cr *= pref; cg *= pref; cb *= pref; cd *= pref;

    // Reduce the 4 partial sums across the 4-lane group: 2 xor steps x 4 vals.
    cr += __shfl_xor(cr, 1); cg += __shfl_xor(cg, 1);
    cb += __shfl_xor(cb, 1); cd += __shfl_xor(cd, 1);
    cr += __shfl_xor(cr, 2); cg += __shfl_xor(cg, 2);
    cb += __shfl_xor(cb, 2); cd += __shfl_xor(cd, 2);

    if (q == 0) {
        float* out = rgb_map + (size_t)ray * 3;
        out[0] = cr; out[1] = cg; out[2] = cb;
        depth_map[ray] = cd;
    }
}

extern "C" void kernel_launch(void* const* d_in, const int* in_sizes, int n_in,
                              void* d_out, int out_size, void* d_ws, size_t ws_size,
                              hipStream_t stream) {
    const float* rgb   = (const float*)d_in[0];   // [B, 64, 3]
    const float* sigma = (const float*)d_in[1];   // [B, 64]
    const int n_rays = in_sizes[1] / NSAMP;

    float* rgb_map   = (float*)d_out;                        // first B*3 floats
    float* depth_map = (float*)d_out + (size_t)n_rays * 3;   // next B floats

    const int threads = 256;
    const int total   = n_rays * TPR;
    const int blocks  = (total + threads - 1) / threads;
    nerf_render_kernel<<<blocks, threads, 0, stream>>>(
        rgb, sigma, rgb_map, depth_map, n_rays);
}

// Round 3
// 310.800 us; speedup vs baseline: 1.0309x; 1.0309x over previous
//
#include <hip/hip_runtime.h>

// NeRF volume render: B rays x S=64 samples.
// 16 threads per ray, 4 samples per thread.
//   sigma: one float4/thread, lane-stride 16B -> perfectly coalesced stream.
//   rgb:   three float4/thread, lane-stride 48B -> dense 3KB/wave span.
// Sequential cumprod over 4 local samples, 4-step 16-lane multiplicative
// scan to stitch transmittance, 4-step xor reduction for the 4 outputs.
//
// alpha_i = 1 - exp(-sigma_i); v_i = exp(-sigma_i) + 1e-10
// T_i = prod_{j<i} v_j ; w_i = alpha_i * T_i
// rgb_map = sum w_i * rgb_i ; depth = sum w_i * t_i, t = linspace(2,6,64)

#define NSAMP 64
#define SPT 4            // samples per thread
#define TPR 16           // threads per ray

__global__ __launch_bounds__(256) void nerf_render_kernel(
    const float* __restrict__ rgb,     // [B, 64, 3]
    const float* __restrict__ sigma,   // [B, 64]
    float* __restrict__ rgb_map,       // [B, 3]
    float* __restrict__ depth_map,     // [B]
    int n_rays)
{
    const int tid = blockIdx.x * blockDim.x + threadIdx.x;
    const int ray = tid >> 4;          // 16 threads per ray
    const int q   = tid & 15;          // sixteenth index
    if (ray >= n_rays) return;

    // sigma: floats [4*tid, 4*tid+4) -> one float4 at byte offset 16*tid.
    float4 s4 = ((const float4*)sigma)[tid];
    // rgb: floats [12*tid, 12*tid+12) -> 3 float4 at byte offset 48*tid.
    const float4* rg4 = (const float4*)(rgb + (size_t)tid * (SPT * 3));
    float4 c0 = rg4[0];
    float4 c1 = rg4[1];
    float4 c2 = rg4[2];

    const float sg[SPT]     = { s4.x, s4.y, s4.z, s4.w };
    const float rg[SPT * 3] = { c0.x, c0.y, c0.z, c0.w,
                                c1.x, c1.y, c1.z, c1.w,
                                c2.x, c2.y, c2.z, c2.w };

    const float tstep = 4.0f / 63.0f;
    const float tbase = 2.0f + (float)(q * SPT) * tstep;
    float T = 1.0f;
    float cr = 0.0f, cg = 0.0f, cb = 0.0f, cd = 0.0f;
    #pragma unroll
    for (int j = 0; j < SPT; ++j) {
        float e = __expf(-sg[j]);
        float a = 1.0f - e;          // alpha
        float v = e + 1e-10f;        // 1 - alpha + eps
        float w = a * T;
        T *= v;
        cr = fmaf(w, rg[3*j+0], cr);
        cg = fmaf(w, rg[3*j+1], cg);
        cb = fmaf(w, rg[3*j+2], cb);
        cd = fmaf(w, tbase + (float)j * tstep, cd);
    }

    // T = product of v over this thread's 4 samples. Exclusive multiplicative
    // prefix across the 16 lanes of this ray (4-step Hillis-Steele + shift).
    float P = T;
    float o;
    o = __shfl_up(P, 1, TPR); if (q >= 1) P *= o;
    o = __shfl_up(P, 2, TPR); if (q >= 2) P *= o;
    o = __shfl_up(P, 4, TPR); if (q >= 4) P *= o;
    o = __shfl_up(P, 8, TPR); if (q >= 8) P *= o;
    float pref = __shfl_up(P, 1, TPR); if (q == 0) pref = 1.0f;

    cr *= pref; cg *= pref; cb *= pref; cd *= pref;

    // Reduce partial sums across the 16-lane group (xor<16 stays in-group).
    #pragma unroll
    for (int d = 8; d >= 1; d >>= 1) {
        cr += __shfl_xor(cr, d);
        cg += __shfl_xor(cg, d);
        cb += __shfl_xor(cb, d);
        cd += __shfl_xor(cd, d);
    }

    if (q == 0) {
        float* out = rgb_map + (size_t)ray * 3;
        out[0] = cr; out[1] = cg; out[2] = cb;
        depth_map[ray] = cd;
    }
}

extern "C" void kernel_launch(void* const* d_in, const int* in_sizes, int n_in,
                              void* d_out, int out_size, void* d_ws, size_t ws_size,
                              hipStream_t stream) {
    const float* rgb   = (const float*)d_in[0];   // [B, 64, 3]
    const float* sigma = (const float*)d_in[1];   // [B, 64]
    const int n_rays = in_sizes[1] / NSAMP;

    float* rgb_map   = (float*)d_out;                        // first B*3 floats
    float* depth_map = (float*)d_out + (size_t)n_rays * 3;   // next B floats

    const int threads = 256;
    const int total   = n_rays * TPR;
    const int blocks  = (total + threads - 1) / threads;
    nerf_render_kernel<<<blocks, threads, 0, stream>>>(
        rgb, sigma, rgb_map, depth_map, n_rays);
}